// Round 3
// baseline (2134.469 us; speedup 1.0000x reference)
//
#include <hip/hip_runtime.h>

#define NTOK (32*4096)           // 131072 tokens
#define WQ_FLOATS (5*144*32)     // fused qkv weights

// ---------- setup: fold agg_W/agg_b through in_proj into W_qkv/b_qkv ----------
__global__ void setup_wqkv(const float* __restrict__ aggW,   // (5,48,32)
                           const float* __restrict__ aggB,   // (5,48)
                           const float* __restrict__ ipw,    // (144,48)
                           const float* __restrict__ ipb,    // (144,)
                           float* __restrict__ Wq,           // (5,144,32)
                           float* __restrict__ bq)           // (5,144)
{
    int t = blockIdx.x*256 + threadIdx.x;
    if (t >= 5*144) return;
    int a = t / 144;
    int r = t - a*144;
    float scale = (r < 48) ? 0.20412414523193154f : 1.0f;    // 1/sqrt(24)
    const float* wrow = ipw + r*48;
    float bacc = ipb[r];
    for (int e = 0; e < 48; ++e) bacc += wrow[e]*aggB[a*48 + e];
    bq[t] = bacc*scale;
    for (int d = 0; d < 32; ++d) {
        float acc = 0.f;
        for (int e = 0; e < 48; ++e) acc += wrow[e]*aggW[(a*48 + e)*32 + d];
        Wq[t*32 + d] = acc*scale;
    }
}

__device__ __forceinline__ void load_xchunk(const float* __restrict__ p, float xr[32])
{
    const float4* xv = reinterpret_cast<const float4*>(p);
#pragma unroll
    for (int i = 0; i < 8; ++i) {
        float4 t = xv[i];
        xr[4*i+0] = t.x; xr[4*i+1] = t.y; xr[4*i+2] = t.z; xr[4*i+3] = t.w;
    }
}

// 48 fused-qkv rows [ROWBASE, ROWBASE+48). Weight loads go through the VECTOR pipe
// (per-lane addr via opaque-zero vz) so vmcnt-depth pipelining hides latency; all
// lanes hit the same cache line (broadcast).
template<int ROWBASE>
__device__ __forceinline__ void qkv_rows48(const float* __restrict__ Wq,
                                           const float* __restrict__ bq,
                                           unsigned wa, unsigned w0, int npass, int vz,
                                           const float xr[32], float t[48])
{
#pragma unroll 1
    for (int p = 0; p < npass; ++p) {
        const unsigned w = p ? (w0 == 4u ? 0u : w0 + 1u) : w0;
        const float4* __restrict__ Wb =
            reinterpret_cast<const float4*>(Wq + (w*144u + (unsigned)ROWBASE)*32u);
        const float* __restrict__ Bb = bq + w*144u + (unsigned)ROWBASE;
        const bool keep = (p == 0) || (wa == w);
#pragma unroll
        for (int e = 0; e < 48; ++e) {
            float4 w0v = Wb[e*8 + 0 + vz];
            float4 w1v = Wb[e*8 + 1 + vz];
            float4 w2v = Wb[e*8 + 2 + vz];
            float4 w3v = Wb[e*8 + 3 + vz];
            float4 w4v = Wb[e*8 + 4 + vz];
            float4 w5v = Wb[e*8 + 5 + vz];
            float4 w6v = Wb[e*8 + 6 + vz];
            float4 w7v = Wb[e*8 + 7 + vz];
            float acc = Bb[e + vz];
            acc = fmaf(w0v.x, xr[0],  acc); acc = fmaf(w0v.y, xr[1],  acc);
            acc = fmaf(w0v.z, xr[2],  acc); acc = fmaf(w0v.w, xr[3],  acc);
            acc = fmaf(w1v.x, xr[4],  acc); acc = fmaf(w1v.y, xr[5],  acc);
            acc = fmaf(w1v.z, xr[6],  acc); acc = fmaf(w1v.w, xr[7],  acc);
            acc = fmaf(w2v.x, xr[8],  acc); acc = fmaf(w2v.y, xr[9],  acc);
            acc = fmaf(w2v.z, xr[10], acc); acc = fmaf(w2v.w, xr[11], acc);
            acc = fmaf(w3v.x, xr[12], acc); acc = fmaf(w3v.y, xr[13], acc);
            acc = fmaf(w3v.z, xr[14], acc); acc = fmaf(w3v.w, xr[15], acc);
            acc = fmaf(w4v.x, xr[16], acc); acc = fmaf(w4v.y, xr[17], acc);
            acc = fmaf(w4v.z, xr[18], acc); acc = fmaf(w4v.w, xr[19], acc);
            acc = fmaf(w5v.x, xr[20], acc); acc = fmaf(w5v.y, xr[21], acc);
            acc = fmaf(w5v.z, xr[22], acc); acc = fmaf(w5v.w, xr[23], acc);
            acc = fmaf(w6v.x, xr[24], acc); acc = fmaf(w6v.y, xr[25], acc);
            acc = fmaf(w6v.z, xr[26], acc); acc = fmaf(w6v.w, xr[27], acc);
            acc = fmaf(w7v.x, xr[28], acc); acc = fmaf(w7v.y, xr[29], acc);
            acc = fmaf(w7v.z, xr[30], acc); acc = fmaf(w7v.w, xr[31], acc);
            t[e] = keep ? acc : t[e];
        }
    }
}

// ---------- main attention kernel: one thread = one (token, row) ----------
__global__ __launch_bounds__(256) void attn_main(
    const float* __restrict__ x,     // (32,4096,256)
    const float* __restrict__ Wq,    // (5,144,32) fused
    const float* __restrict__ bq,    // (5,144)
    const float* __restrict__ outw,  // (48,48)
    const float* __restrict__ outb,  // (48,)
    float* __restrict__ out)         // (32,4096,512), cols [0,240)
{
    const int lane = (int)(threadIdx.x & 63u);
    if (lane >= 60) return;
    const int wv = (int)(threadIdx.x >> 6u);
    const unsigned m_base = (blockIdx.x*4u + (unsigned)wv)*12u;
    const unsigned tok5 = (unsigned)lane / 5u;
    const unsigned aq   = (unsigned)lane - tok5*5u;
    const unsigned m = m_base + tok5;
    if (m >= NTOK) return;

    int vz = 0;
    asm volatile("" : "+v"(vz));     // opaque zero -> forces vector-pipe weight loads

    const unsigned g  = 5u*m_base + (unsigned)lane;     // == 5m + aq
    const unsigned u  = g >> 12;                        // < 160
    const unsigned bb = (u*52429u) >> 18;               // u/5
    const unsigned a  = u - 5u*bb;                      // u%5 -> weight index
    const float* xp = x + ((((bb<<12) | (g & 4095u)) << 8) + (a<<5));

    const unsigned w0 = (unsigned)__builtin_amdgcn_readfirstlane((int)a);
    const int npass = __all((int)(a == w0)) ? 1 : 2;

    // ---------- q,k for my row ----------
    float q[48], k[48];
    {
        float xr[32]; load_xchunk(xp, xr);
        qkv_rows48<0>(Wq, bq, a, w0, npass, vz, xr, q);
        qkv_rows48<48>(Wq, bq, a, w0, npass, vz, xr, k);
    }

    // ---------- scores via k-rotation ----------
    const int base4 = (lane - (int)aq)*4;
    float s0[5], s1[5];
    {
        float a0 = 0.f, a1 = 0.f;
#pragma unroll
        for (int e = 0; e < 24; ++e) a0 = fmaf(q[e], k[e], a0);
#pragma unroll
        for (int e = 24; e < 48; ++e) a1 = fmaf(q[e], k[e], a1);
        s0[0] = a0; s1[0] = a1;
    }
#pragma unroll
    for (int r = 1; r < 5; ++r) {
        int sl = (int)aq + r; sl = (sl >= 5) ? sl - 5 : sl;
        const int addr = base4 + sl*4;
        float a0 = 0.f, a1 = 0.f;
#pragma unroll
        for (int e = 0; e < 48; ++e) {
            float kr = __int_as_float(__builtin_amdgcn_ds_bpermute(addr, __float_as_int(k[e])));
            if (e < 24) a0 = fmaf(q[e], kr, a0);
            else        a1 = fmaf(q[e], kr, a1);
        }
        s0[r] = a0; s1[r] = a1;
    }

    // ---------- softmax ----------
    float p0[5], p1[5];
    {
        float mx = fmaxf(fmaxf(fmaxf(s0[0], s0[1]), fmaxf(s0[2], s0[3])), s0[4]);
        float e0 = __expf(s0[0]-mx), e1 = __expf(s0[1]-mx), e2 = __expf(s0[2]-mx),
              e3 = __expf(s0[3]-mx), e4 = __expf(s0[4]-mx);
        float inv = 1.0f/(e0+e1+e2+e3+e4);
        p0[0]=e0*inv; p0[1]=e1*inv; p0[2]=e2*inv; p0[3]=e3*inv; p0[4]=e4*inv;
    }
    {
        float mx = fmaxf(fmaxf(fmaxf(s1[0], s1[1]), fmaxf(s1[2], s1[3])), s1[4]);
        float e0 = __expf(s1[0]-mx), e1 = __expf(s1[1]-mx), e2 = __expf(s1[2]-mx),
              e3 = __expf(s1[3]-mx), e4 = __expf(s1[4]-mx);
        float inv = 1.0f/(e0+e1+e2+e3+e4);
        p1[0]=e0*inv; p1[1]=e1*inv; p1[2]=e2*inv; p1[3]=e3*inv; p1[4]=e4*inv;
    }

    // ---------- v for my row ----------
    float v[48];
    {
        float xr[32]; load_xchunk(xp, xr);
        qkv_rows48<96>(Wq, bq, a, w0, npass, vz, xr, v);
    }

    // ---------- PV via v-rotation ----------
    float o[48];
#pragma unroll
    for (int e = 0; e < 48; ++e) o[e] = ((e < 24) ? p0[0] : p1[0]) * v[e];
#pragma unroll
    for (int r = 1; r < 5; ++r) {
        int sl = (int)aq + r; sl = (sl >= 5) ? sl - 5 : sl;
        const int addr = base4 + sl*4;
#pragma unroll
        for (int e = 0; e < 48; ++e) {
            float vr = __int_as_float(__builtin_amdgcn_ds_bpermute(addr, __float_as_int(v[e])));
            o[e] = fmaf((e < 24) ? p0[r] : p1[r], vr, o[e]);
        }
    }

    // ---------- out-proj (48x48), vector weight loads ----------
    float* __restrict__ dst = out + (size_t)m*512u + aq*48u;
#pragma unroll 1
    for (int e8 = 0; e8 < 6; ++e8) {
        float acc[8];
#pragma unroll
        for (int j = 0; j < 8; ++j) {
            const float4* __restrict__ wrow =
                reinterpret_cast<const float4*>(outw + (e8*8 + j)*48);
            float s = outb[e8*8 + j + vz];
#pragma unroll
            for (int f4 = 0; f4 < 12; ++f4) {
                float4 wv4 = wrow[f4 + vz];
                s = fmaf(wv4.x, o[4*f4+0], s);
                s = fmaf(wv4.y, o[4*f4+1], s);
                s = fmaf(wv4.z, o[4*f4+2], s);
                s = fmaf(wv4.w, o[4*f4+3], s);
            }
            acc[j] = s;
        }
        float4* d4 = reinterpret_cast<float4*>(dst + e8*8);
        d4[0] = make_float4(acc[0], acc[1], acc[2], acc[3]);
        d4[1] = make_float4(acc[4], acc[5], acc[6], acc[7]);
    }
}

// ---------- extra path: weights-in-VGPR, wave = 16 out cols, lane = (col, d-seg) ----------
__global__ __launch_bounds__(256) void extra_kernel(
    const float* __restrict__ x,     // (32,4096,256)
    const float* __restrict__ exw,   // (272,96)
    const float* __restrict__ exb,   // (272,)
    float* __restrict__ out)         // cols [240,512)
{
    const int lane = (int)(threadIdx.x & 63u);
    const int wv   = (int)(threadIdx.x >> 6u);
    const unsigned gw = blockIdx.x*4u + (unsigned)wv;   // 0..8703
    const unsigned c  = gw % 17u;                        // col group
    const unsigned strip = gw / 17u;                     // 0..511
    const unsigned m0 = strip*256u;

    const int col16 = lane & 15;
    const int dseg  = lane >> 4;                         // 0..3
    const int dbase = dseg*24;
    const unsigned j = c*16u + (unsigned)col16;          // out col (0..271)

    float w[24];
    {
        const float4* wp = reinterpret_cast<const float4*>(exw + j*96u + (unsigned)dbase);
#pragma unroll
        for (int i = 0; i < 6; ++i) {
            float4 t = wp[i];
            w[4*i+0]=t.x; w[4*i+1]=t.y; w[4*i+2]=t.z; w[4*i+3]=t.w;
        }
    }
    const float bias = exb[j];

#pragma unroll 4
    for (unsigned mm = 0; mm < 256u; ++mm) {
        const unsigned m = m0 + mm;
        const float4* xp = reinterpret_cast<const float4*>(x + (size_t)m*256u + 160u + (unsigned)dbase);
        float acc = 0.f;
#pragma unroll
        for (int i = 0; i < 6; ++i) {
            float4 t = xp[i];
            acc = fmaf(w[4*i+0], t.x, acc);
            acc = fmaf(w[4*i+1], t.y, acc);
            acc = fmaf(w[4*i+2], t.z, acc);
            acc = fmaf(w[4*i+3], t.w, acc);
        }
        acc += __shfl_xor(acc, 16);
        acc += __shfl_xor(acc, 32);
        if (lane < 16)
            out[(size_t)m*512u + 240u + j] = acc + bias;
    }
}

// ---------------- launch ----------------
extern "C" void kernel_launch(void* const* d_in, const int* in_sizes, int n_in,
                              void* d_out, int out_size, void* d_ws, size_t ws_size,
                              hipStream_t stream)
{
    const float* x    = (const float*)d_in[0];
    const float* aggW = (const float*)d_in[1];
    const float* aggB = (const float*)d_in[2];
    const float* ipw  = (const float*)d_in[3];
    const float* ipb  = (const float*)d_in[4];
    const float* outw = (const float*)d_in[5];
    const float* outb = (const float*)d_in[6];
    const float* exw  = (const float*)d_in[7];
    const float* exb  = (const float*)d_in[8];
    float* out = (float*)d_out;

    float* Wq = (float*)d_ws;                 // 23040 floats
    float* bq = Wq + WQ_FLOATS;               // 720 floats

    setup_wqkv<<<dim3(3), dim3(256), 0, stream>>>(aggW, aggB, ipw, ipb, Wq, bq);
    attn_main<<<dim3((NTOK + 47)/48), dim3(256), 0, stream>>>(x, Wq, bq, outw, outb, out);
    // 17 col-groups x 512 strips of 256 tokens, 4 waves/block
    extra_kernel<<<dim3(17*512/4), dim3(256), 0, stream>>>(x, exw, exb, out);
}

// Round 4
// 1040.194 us; speedup vs baseline: 2.0520x; 2.0520x over previous
//
#include <hip/hip_runtime.h>

#define NTOK (32*4096)           // 131072 tokens
#define WQ_FLOATS (5*144*32)     // fused qkv weights

// ---------- setup: fold agg_W/agg_b through in_proj into W_qkv/b_qkv ----------
__global__ void setup_wqkv(const float* __restrict__ aggW,   // (5,48,32)
                           const float* __restrict__ aggB,   // (5,48)
                           const float* __restrict__ ipw,    // (144,48)
                           const float* __restrict__ ipb,    // (144,)
                           float* __restrict__ Wq,           // (5,144,32)
                           float* __restrict__ bq)           // (5,144)
{
    int t = blockIdx.x*256 + threadIdx.x;
    if (t >= 5*144) return;
    int a = t / 144;
    int r = t - a*144;
    float scale = (r < 48) ? 0.20412414523193154f : 1.0f;    // 1/sqrt(24)
    const float* wrow = ipw + r*48;
    float bacc = ipb[r];
    for (int e = 0; e < 48; ++e) bacc += wrow[e]*aggB[a*48 + e];
    bq[t] = bacc*scale;
    for (int d = 0; d < 32; ++d) {
        float acc = 0.f;
        for (int e = 0; e < 48; ++e) acc += wrow[e]*aggW[(a*48 + e)*32 + d];
        Wq[t*32 + d] = acc*scale;
    }
}

__device__ __forceinline__ void load_xchunk(const float* __restrict__ p, float xr[32])
{
    const float4* xv = reinterpret_cast<const float4*>(p);
#pragma unroll
    for (int i = 0; i < 8; ++i) {
        float4 t = xv[i];
        xr[4*i+0] = t.x; xr[4*i+1] = t.y; xr[4*i+2] = t.z; xr[4*i+3] = t.w;
    }
}

// 32-term dot against an LDS weight row (8 uniform ds_read_b128 broadcasts)
__device__ __forceinline__ float row32(const float* __restrict__ wrow, const float xr[32], float acc)
{
    const float4* wp = reinterpret_cast<const float4*>(wrow);
#pragma unroll
    for (int i = 0; i < 8; ++i) {
        float4 w4 = wp[i];
        acc = fmaf(w4.x, xr[4*i+0], acc);
        acc = fmaf(w4.y, xr[4*i+1], acc);
        acc = fmaf(w4.z, xr[4*i+2], acc);
        acc = fmaf(w4.w, xr[4*i+3], acc);
    }
    return acc;
}

// ---------- main attention kernel: one thread = one (token, row) ----------
// Row a2 of token m is flat row g = 5m+a2; (u=g>>12, b=u/5, a=u%5, n=g&4095);
// x chunk = x[(b*4096+n)*256 + a*32 ..+32). Block = 48 tokens = 240 flat rows ->
// at most 2 weight indices {a0,(a0+1)%5}: both staged in LDS. Weight reads are
// wave-uniform ds_read_b128 broadcasts. k/v are streamed with immediate
// score/PV accumulation so they never occupy 48 VGPRs.
__global__ __launch_bounds__(256) void attn_main(
    const float* __restrict__ x,     // (32,4096,256)
    const float* __restrict__ Wq,    // (5,144,32) fused
    const float* __restrict__ bq,    // (5,144)
    const float* __restrict__ outw,  // (48,48)
    const float* __restrict__ outb,  // (48,)
    float* __restrict__ out)         // (32,4096,512), cols [0,240)
{
    __shared__ float sAll[11856];
    float* sW  = sAll;          // [2][144*32]
    float* sB  = sAll + 9216;   // [2][144]
    float* sOW = sAll + 9504;   // [48*48]
    float* sOB = sAll + 11808;  // [48]

    const int t = (int)threadIdx.x;
    const unsigned g0 = blockIdx.x * 240u;
    const unsigned u0 = g0 >> 12;
    const unsigned a0 = u0 - 5u*((u0*52429u) >> 18);
    const unsigned a1 = (a0 == 4u) ? 0u : a0 + 1u;

    // ---- stage weights (all 256 threads) ----
    {
        const float4* s0p = reinterpret_cast<const float4*>(Wq + a0*4608u);
        const float4* s1p = reinterpret_cast<const float4*>(Wq + a1*4608u);
        float4* d0 = reinterpret_cast<float4*>(sW);
        float4* d1 = reinterpret_cast<float4*>(sW + 4608);
#pragma unroll
        for (int i = 0; i < 5; ++i) {
            int idx = t + 256*i;
            if (idx < 1152) { d0[idx] = s0p[idx]; d1[idx] = s1p[idx]; }
        }
        const float4* owp = reinterpret_cast<const float4*>(outw);
        float4* dow = reinterpret_cast<float4*>(sOW);
#pragma unroll
        for (int i = 0; i < 3; ++i) {
            int idx = t + 256*i;
            if (idx < 576) dow[idx] = owp[idx];
        }
        if (t < 144) { sB[t] = bq[a0*144u + t]; sB[144 + t] = bq[a1*144u + t]; }
        if (t >= 192 && t < 240) sOB[t - 192] = outb[t - 192];
    }
    __syncthreads();

    const int lane = t & 63;
    const int wv   = t >> 6;
    if (lane >= 60) return;
    const unsigned m_base = (blockIdx.x*4u + (unsigned)wv)*12u;
    const unsigned tok5 = (unsigned)lane / 5u;
    const unsigned aq   = (unsigned)lane - tok5*5u;
    const unsigned m = m_base + tok5;
    if (m >= NTOK) return;

    const unsigned g  = 5u*m_base + (unsigned)lane;     // == 5m + aq
    const unsigned u  = g >> 12;
    const unsigned bb = (u*52429u) >> 18;
    const unsigned a  = u - 5u*bb;
    const float* xp = x + ((((bb<<12) | (g & 4095u)) << 8) + (a<<5));

    const int sel = (a == a0) ? 0 : 1;
    const float* myW = sW + sel*4608;
    const float* myB = sB + sel*144;

    float xr[32]; load_xchunk(xp, xr);

    // bpermute addresses for rotations r=1..4 within my 5-lane token group
    const int base4 = (lane - (int)aq)*4;
    int ad[4];
#pragma unroll
    for (int r = 0; r < 4; ++r) {
        int sl = (int)aq + r + 1; if (sl >= 5) sl -= 5;
        ad[r] = base4 + sl*4;
    }

    // ---------- Q rows ----------
    float q[48];
#pragma unroll
    for (int e = 0; e < 48; ++e)
        q[e] = row32(myW + e*32, xr, myB[e]);

    // ---------- K stream with immediate score accumulation ----------
    float s0[5] = {0,0,0,0,0}, s1[5] = {0,0,0,0,0};
#pragma unroll
    for (int e = 0; e < 48; ++e) {
        float kv = row32(myW + (48+e)*32, xr, myB[48+e]);
        float qe = q[e];
        float* sh = (e < 24) ? s0 : s1;       // e is compile-time (full unroll)
        sh[0] = fmaf(qe, kv, sh[0]);
#pragma unroll
        for (int r = 0; r < 4; ++r) {
            float kr = __int_as_float(__builtin_amdgcn_ds_bpermute(ad[r], __float_as_int(kv)));
            sh[r+1] = fmaf(qe, kr, sh[r+1]);
        }
    }

    // ---------- softmax (scale folded into q weights) ----------
    float p0[5], p1[5];
    {
        float mx = fmaxf(fmaxf(fmaxf(s0[0], s0[1]), fmaxf(s0[2], s0[3])), s0[4]);
        float e0 = __expf(s0[0]-mx), e1 = __expf(s0[1]-mx), e2 = __expf(s0[2]-mx),
              e3 = __expf(s0[3]-mx), e4 = __expf(s0[4]-mx);
        float inv = 1.0f/(e0+e1+e2+e3+e4);
        p0[0]=e0*inv; p0[1]=e1*inv; p0[2]=e2*inv; p0[3]=e3*inv; p0[4]=e4*inv;
    }
    {
        float mx = fmaxf(fmaxf(fmaxf(s1[0], s1[1]), fmaxf(s1[2], s1[3])), s1[4]);
        float e0 = __expf(s1[0]-mx), e1 = __expf(s1[1]-mx), e2 = __expf(s1[2]-mx),
              e3 = __expf(s1[3]-mx), e4 = __expf(s1[4]-mx);
        float inv = 1.0f/(e0+e1+e2+e3+e4);
        p1[0]=e0*inv; p1[1]=e1*inv; p1[2]=e2*inv; p1[3]=e3*inv; p1[4]=e4*inv;
    }

    // ---------- V stream with immediate PV accumulation ----------
    float o[48];
#pragma unroll
    for (int e = 0; e < 48; ++e) {
        float vv = row32(myW + (96+e)*32, xr, myB[96+e]);
        const float* pp = (e < 24) ? p0 : p1; // compile-time
        float acc = pp[0]*vv;
#pragma unroll
        for (int r = 0; r < 4; ++r) {
            float vr = __int_as_float(__builtin_amdgcn_ds_bpermute(ad[r], __float_as_int(vv)));
            acc = fmaf(pp[r+1], vr, acc);
        }
        o[e] = acc;
    }

    // ---------- out-proj (48x48) from LDS + store ----------
    float* __restrict__ dst = out + (size_t)m*512u + aq*48u;
#pragma unroll 1
    for (int j8 = 0; j8 < 6; ++j8) {
        float acc[8];
#pragma unroll
        for (int j = 0; j < 8; ++j) {
            const float* wrow = sOW + (j8*8 + j)*48;
            float s = sOB[j8*8 + j];
            const float4* wr4 = reinterpret_cast<const float4*>(wrow);
#pragma unroll
            for (int f4 = 0; f4 < 12; ++f4) {
                float4 w4 = wr4[f4];
                s = fmaf(w4.x, o[4*f4+0], s);
                s = fmaf(w4.y, o[4*f4+1], s);
                s = fmaf(w4.z, o[4*f4+2], s);
                s = fmaf(w4.w, o[4*f4+3], s);
            }
            acc[j] = s;
        }
        float4* d4 = reinterpret_cast<float4*>(dst + j8*8);
        d4[0] = make_float4(acc[0], acc[1], acc[2], acc[3]);
        d4[1] = make_float4(acc[4], acc[5], acc[6], acc[7]);
    }
}

// ---------- extra path: weights-in-VGPR + explicit 2-deep prefetch pipeline ----------
__global__ __launch_bounds__(256) void extra_kernel(
    const float* __restrict__ x,     // (32,4096,256)
    const float* __restrict__ exw,   // (272,96)
    const float* __restrict__ exb,   // (272,)
    float* __restrict__ out)         // cols [240,512)
{
    const int lane = (int)(threadIdx.x & 63u);
    const int wv   = (int)(threadIdx.x >> 6u);
    const unsigned gw = blockIdx.x*4u + (unsigned)wv;   // 0..17407
    const unsigned c  = gw % 17u;                        // col group
    const unsigned strip = gw / 17u;                     // 0..1023
    const unsigned m0 = strip*128u;

    const int col16 = lane & 15;
    const int dseg  = lane >> 4;                         // 0..3
    const unsigned j = c*16u + (unsigned)col16;          // out col (0..271)

    float w[24];
    {
        const float4* wp = reinterpret_cast<const float4*>(exw + (size_t)j*96u + (unsigned)(dseg*24));
#pragma unroll
        for (int i = 0; i < 6; ++i) {
            float4 v = wp[i];
            w[4*i+0]=v.x; w[4*i+1]=v.y; w[4*i+2]=v.z; w[4*i+3]=v.w;
        }
    }
    const float bias = exb[j];
    const float* xb = x + 160u + (unsigned)(dseg*24);

    float4 A[6], Bv[6];
    {
        const float4* p = reinterpret_cast<const float4*>(xb + (size_t)m0*256u);
#pragma unroll
        for (int i = 0; i < 6; ++i) A[i] = p[i];
    }
    {
        const float4* p = reinterpret_cast<const float4*>(xb + (size_t)(m0+1)*256u);
#pragma unroll
        for (int i = 0; i < 6; ++i) Bv[i] = p[i];
    }

#pragma unroll 1
    for (int i = 0; i < 128; i += 2) {
        // ---- token m0+i from A ----
        float acc = 0.f;
#pragma unroll
        for (int s = 0; s < 6; ++s) {
            acc = fmaf(w[4*s+0], A[s].x, acc);
            acc = fmaf(w[4*s+1], A[s].y, acc);
            acc = fmaf(w[4*s+2], A[s].z, acc);
            acc = fmaf(w[4*s+3], A[s].w, acc);
        }
        {   // prefetch i+2 (wraps within strip; always in-bounds)
            const float4* p = reinterpret_cast<const float4*>(xb + (size_t)(m0 + ((i+2) & 127))*256u);
#pragma unroll
            for (int s = 0; s < 6; ++s) A[s] = p[s];
        }
        acc += __shfl_xor(acc, 16);
        acc += __shfl_xor(acc, 32);
        if (lane < 16) out[(size_t)(m0 + i)*512u + 240u + j] = acc + bias;

        // ---- token m0+i+1 from Bv ----
        float acc2 = 0.f;
#pragma unroll
        for (int s = 0; s < 6; ++s) {
            acc2 = fmaf(w[4*s+0], Bv[s].x, acc2);
            acc2 = fmaf(w[4*s+1], Bv[s].y, acc2);
            acc2 = fmaf(w[4*s+2], Bv[s].z, acc2);
            acc2 = fmaf(w[4*s+3], Bv[s].w, acc2);
        }
        {   // prefetch i+3
            const float4* p = reinterpret_cast<const float4*>(xb + (size_t)(m0 + ((i+3) & 127))*256u);
#pragma unroll
            for (int s = 0; s < 6; ++s) Bv[s] = p[s];
        }
        acc2 += __shfl_xor(acc2, 16);
        acc2 += __shfl_xor(acc2, 32);
        if (lane < 16) out[(size_t)(m0 + i + 1)*512u + 240u + j] = acc2 + bias;
    }
}

// ---------------- launch ----------------
extern "C" void kernel_launch(void* const* d_in, const int* in_sizes, int n_in,
                              void* d_out, int out_size, void* d_ws, size_t ws_size,
                              hipStream_t stream)
{
    const float* x    = (const float*)d_in[0];
    const float* aggW = (const float*)d_in[1];
    const float* aggB = (const float*)d_in[2];
    const float* ipw  = (const float*)d_in[3];
    const float* ipb  = (const float*)d_in[4];
    const float* outw = (const float*)d_in[5];
    const float* outb = (const float*)d_in[6];
    const float* exw  = (const float*)d_in[7];
    const float* exb  = (const float*)d_in[8];
    float* out = (float*)d_out;

    float* Wq = (float*)d_ws;                 // 23040 floats
    float* bq = Wq + WQ_FLOATS;               // 720 floats

    setup_wqkv<<<dim3(3), dim3(256), 0, stream>>>(aggW, aggB, ipw, ipb, Wq, bq);
    // 48 tokens per 256-thread block (12 per wave, lanes 0..59)
    attn_main<<<dim3((NTOK + 47)/48), dim3(256), 0, stream>>>(x, Wq, bq, outw, outb, out);
    // 17 col-groups x 1024 strips of 128 tokens, 4 waves/block
    extra_kernel<<<dim3(17*1024/4), dim3(256), 0, stream>>>(x, exw, exb, out);
}

// Round 5
// 822.741 us; speedup vs baseline: 2.5943x; 1.2643x over previous
//
#include <hip/hip_runtime.h>

#define NTOK (32*4096)           // 131072 tokens
#define WQ_FLOATS (5*144*32)     // fused qkv weights

// ---------- setup: fold agg_W/agg_b through in_proj into W_qkv/b_qkv ----------
__global__ void setup_wqkv(const float* __restrict__ aggW,   // (5,48,32)
                           const float* __restrict__ aggB,   // (5,48)
                           const float* __restrict__ ipw,    // (144,48)
                           const float* __restrict__ ipb,    // (144,)
                           float* __restrict__ Wq,           // (5,144,32)
                           float* __restrict__ bq)           // (5,144)
{
    int t = blockIdx.x*256 + threadIdx.x;
    if (t >= 5*144) return;
    int a = t / 144;
    int r = t - a*144;
    float scale = (r < 48) ? 0.20412414523193154f : 1.0f;    // 1/sqrt(24)
    const float* wrow = ipw + r*48;
    float bacc = ipb[r];
    for (int e = 0; e < 48; ++e) bacc += wrow[e]*aggB[a*48 + e];
    bq[t] = bacc*scale;
    for (int d = 0; d < 32; ++d) {
        float acc = 0.f;
        for (int e = 0; e < 48; ++e) acc += wrow[e]*aggW[(a*48 + e)*32 + d];
        Wq[t*32 + d] = acc*scale;
    }
}

__device__ __forceinline__ void load_xchunk(const float* __restrict__ p, float xr[32])
{
    const float4* xv = reinterpret_cast<const float4*>(p);
#pragma unroll
    for (int i = 0; i < 8; ++i) {
        float4 t = xv[i];
        xr[4*i+0] = t.x; xr[4*i+1] = t.y; xr[4*i+2] = t.z; xr[4*i+3] = t.w;
    }
}

// 32-term dot against an LDS weight row (8 uniform ds_read_b128 broadcasts)
__device__ __forceinline__ float row32(const float* __restrict__ wrow, const float xr[32], float acc)
{
    const float4* wp = reinterpret_cast<const float4*>(wrow);
#pragma unroll
    for (int i = 0; i < 8; ++i) {
        float4 w4 = wp[i];
        acc = fmaf(w4.x, xr[4*i+0], acc);
        acc = fmaf(w4.y, xr[4*i+1], acc);
        acc = fmaf(w4.z, xr[4*i+2], acc);
        acc = fmaf(w4.w, xr[4*i+3], acc);
    }
    return acc;
}

// ---------- attention path: one thread = one (token, row); LOOPY phases ----------
// Row aq of token m is flat row g = 5m+aq; (u=g>>12, b=u/5, a=u%5, n=g&4095);
// x chunk = x[(b*4096+n)*256 + a*32 ..+32). Block = 48 tokens = 240 flat rows ->
// at most 2 weight indices {a0,(a0+1)%5}, both staged in LDS.
// Phases are rolled loops (~1KB bodies, I$-resident); q_e/k_e/v_e are streamed and
// never stored; out-proj is folded into the V loop via transposed outw.
__global__ __launch_bounds__(256) void attn_main(
    const float* __restrict__ x,     // (32,4096,256)
    const float* __restrict__ Wq,    // (5,144,32) fused
    const float* __restrict__ bq,    // (5,144)
    const float* __restrict__ outw,  // (48,48)
    const float* __restrict__ outb,  // (48,)
    float* __restrict__ out)         // (32,4096,512), cols [0,240)
{
    __shared__ float sAll[11856];
    float* sW   = sAll;           // [2][144*32]
    float* sB   = sAll + 9216;    // [2][144]
    float* sOWT = sAll + 9504;    // [48][48]: sOWT[f*48+j] = outw[j*48+f]
    float* sOB  = sAll + 11808;   // [48]

    const int t = (int)threadIdx.x;
    const unsigned g0 = blockIdx.x * 240u;
    const unsigned u0 = g0 >> 12;
    const unsigned a0 = u0 - 5u*((u0*52429u) >> 18);
    const unsigned a1 = (a0 == 4u) ? 0u : a0 + 1u;

    // ---- stage weights (all 256 threads) ----
    {
        const float4* s0p = reinterpret_cast<const float4*>(Wq + a0*4608u);
        const float4* s1p = reinterpret_cast<const float4*>(Wq + a1*4608u);
        float4* d0 = reinterpret_cast<float4*>(sW);
        float4* d1 = reinterpret_cast<float4*>(sW + 4608);
#pragma unroll
        for (int i = 0; i < 5; ++i) {
            int idx = t + 256*i;
            if (idx < 1152) { d0[idx] = s0p[idx]; d1[idx] = s1p[idx]; }
        }
#pragma unroll
        for (int i = 0; i < 9; ++i) {           // 2304 = 9*256 exactly
            int idx = t + 256*i;
            int f = idx / 48, j = idx - f*48;
            sOWT[idx] = outw[j*48 + f];
        }
        if (t < 144) { sB[t] = bq[a0*144u + t]; sB[144 + t] = bq[a1*144u + t]; }
        if (t >= 192 && t < 240) sOB[t - 192] = outb[t - 192];
    }
    __syncthreads();

    const int lane = t & 63;
    if (lane >= 60) return;
    const int wv = t >> 6;
    const unsigned m_base = (blockIdx.x*4u + (unsigned)wv)*12u;
    const unsigned tok5 = (unsigned)lane / 5u;
    const unsigned aq   = (unsigned)lane - tok5*5u;
    const unsigned m = m_base + tok5;
    if (m >= NTOK) return;

    const unsigned g  = 5u*m_base + (unsigned)lane;     // == 5m + aq
    const unsigned u  = g >> 12;
    const unsigned bb = (u*52429u) >> 18;
    const unsigned a  = u - 5u*bb;
    const float* xp = x + ((((bb<<12) | (g & 4095u)) << 8) + (a<<5));

    const int sel = (a == a0) ? 0 : 1;
    const float* myW = sW + sel*4608;
    const float* myB = sB + sel*144;

    float xr[32]; load_xchunk(xp, xr);

    const int base4 = (lane - (int)aq)*4;
    int ad[4];
#pragma unroll
    for (int r = 0; r < 4; ++r) {
        int sl = (int)aq + r + 1; if (sl >= 5) sl -= 5;
        ad[r] = base4 + sl*4;
    }

    // ---------- QK: stream q_e,k_e; accumulate scores ----------
    float s0[5] = {0,0,0,0,0}, s1[5] = {0,0,0,0,0};
#pragma unroll 1
    for (int e = 0; e < 24; ++e) {
        float qe = row32(myW + e*32, xr, myB[e]);
        float ke = row32(myW + (48+e)*32, xr, myB[48+e]);
        s0[0] = fmaf(qe, ke, s0[0]);
#pragma unroll
        for (int r = 0; r < 4; ++r) {
            float kr = __int_as_float(__builtin_amdgcn_ds_bpermute(ad[r], __float_as_int(ke)));
            s0[r+1] = fmaf(qe, kr, s0[r+1]);
        }
    }
#pragma unroll 1
    for (int e = 24; e < 48; ++e) {
        float qe = row32(myW + e*32, xr, myB[e]);
        float ke = row32(myW + (48+e)*32, xr, myB[48+e]);
        s1[0] = fmaf(qe, ke, s1[0]);
#pragma unroll
        for (int r = 0; r < 4; ++r) {
            float kr = __int_as_float(__builtin_amdgcn_ds_bpermute(ad[r], __float_as_int(ke)));
            s1[r+1] = fmaf(qe, kr, s1[r+1]);
        }
    }

    // ---------- softmax (1/sqrt(24) folded into q weights) ----------
    float p0[5], p1[5];
    {
        float mx = fmaxf(fmaxf(fmaxf(s0[0], s0[1]), fmaxf(s0[2], s0[3])), s0[4]);
        float e0 = __expf(s0[0]-mx), e1 = __expf(s0[1]-mx), e2 = __expf(s0[2]-mx),
              e3 = __expf(s0[3]-mx), e4 = __expf(s0[4]-mx);
        float inv = 1.0f/(e0+e1+e2+e3+e4);
        p0[0]=e0*inv; p0[1]=e1*inv; p0[2]=e2*inv; p0[3]=e3*inv; p0[4]=e4*inv;
    }
    {
        float mx = fmaxf(fmaxf(fmaxf(s1[0], s1[1]), fmaxf(s1[2], s1[3])), s1[4]);
        float e0 = __expf(s1[0]-mx), e1 = __expf(s1[1]-mx), e2 = __expf(s1[2]-mx),
              e3 = __expf(s1[3]-mx), e4 = __expf(s1[4]-mx);
        float inv = 1.0f/(e0+e1+e2+e3+e4);
        p1[0]=e0*inv; p1[1]=e1*inv; p1[2]=e2*inv; p1[3]=e3*inv; p1[4]=e4*inv;
    }

    // ---------- V + fused out-proj: out[j] += owT[e][j] * o_e ----------
    float oj[48];
    {
        const float4* b4 = reinterpret_cast<const float4*>(sOB);
#pragma unroll
        for (int j4 = 0; j4 < 12; ++j4) {
            float4 v = b4[j4];
            oj[4*j4+0]=v.x; oj[4*j4+1]=v.y; oj[4*j4+2]=v.z; oj[4*j4+3]=v.w;
        }
    }
#pragma unroll 1
    for (int e = 0; e < 24; ++e) {
        float ve = row32(myW + (96+e)*32, xr, myB[96+e]);
        float oe = p0[0]*ve;
#pragma unroll
        for (int r = 0; r < 4; ++r) {
            float vr = __int_as_float(__builtin_amdgcn_ds_bpermute(ad[r], __float_as_int(ve)));
            oe = fmaf(p0[r+1], vr, oe);
        }
        const float4* owr = reinterpret_cast<const float4*>(sOWT + e*48);
#pragma unroll
        for (int j4 = 0; j4 < 12; ++j4) {
            float4 w4 = owr[j4];
            oj[4*j4+0] = fmaf(w4.x, oe, oj[4*j4+0]);
            oj[4*j4+1] = fmaf(w4.y, oe, oj[4*j4+1]);
            oj[4*j4+2] = fmaf(w4.z, oe, oj[4*j4+2]);
            oj[4*j4+3] = fmaf(w4.w, oe, oj[4*j4+3]);
        }
    }
#pragma unroll 1
    for (int e = 24; e < 48; ++e) {
        float ve = row32(myW + (96+e)*32, xr, myB[96+e]);
        float oe = p1[0]*ve;
#pragma unroll
        for (int r = 0; r < 4; ++r) {
            float vr = __int_as_float(__builtin_amdgcn_ds_bpermute(ad[r], __float_as_int(ve)));
            oe = fmaf(p1[r+1], vr, oe);
        }
        const float4* owr = reinterpret_cast<const float4*>(sOWT + e*48);
#pragma unroll
        for (int j4 = 0; j4 < 12; ++j4) {
            float4 w4 = owr[j4];
            oj[4*j4+0] = fmaf(w4.x, oe, oj[4*j4+0]);
            oj[4*j4+1] = fmaf(w4.y, oe, oj[4*j4+1]);
            oj[4*j4+2] = fmaf(w4.z, oe, oj[4*j4+2]);
            oj[4*j4+3] = fmaf(w4.w, oe, oj[4*j4+3]);
        }
    }

    // ---------- store 48 cols ----------
    float4* d4 = reinterpret_cast<float4*>(out + (size_t)m*512u + aq*48u);
#pragma unroll
    for (int j4 = 0; j4 < 12; ++j4)
        d4[j4] = make_float4(oj[4*j4+0], oj[4*j4+1], oj[4*j4+2], oj[4*j4+3]);
}

// ---------- extra path as LDS-tiled GEMM: (131072x96)@(96x272) ----------
// Block tile: 64 tokens x 288 cols (272 real, 16 pad). x-tile staged once
// (x read exactly once from HBM); w staged in 6 k-panels of 16. Thread tile
// 4 tokens x 18 cols. LDS pads chosen conflict-free (x:97, w:292).
__global__ __launch_bounds__(256) void extra_gemm(
    const float* __restrict__ x,     // (32,4096,256)
    const float* __restrict__ exw,   // (272,96)
    const float* __restrict__ exb,   // (272,)
    float* __restrict__ out)         // cols [240,512)
{
    __shared__ float sx[64*97];      // [tok][k], row pad 97
    __shared__ float sw[16*292];     // [k][col], row pad 292 (288 cols used)

    const int t = (int)threadIdx.x;
    const unsigned m0 = blockIdx.x*64u;

    // ---- stage x-tile: 64 tokens x 96 floats (f4 reads, b32 writes) ----
#pragma unroll
    for (int i = 0; i < 6; ++i) {
        int idx = t + 256*i;                   // 0..1535
        int row = idx / 24, c4 = idx - row*24;
        float4 v = *reinterpret_cast<const float4*>(
            x + (size_t)(m0 + (unsigned)row)*256u + 160u + (unsigned)(c4*4));
        float* dp = sx + row*97 + c4*4;
        dp[0]=v.x; dp[1]=v.y; dp[2]=v.z; dp[3]=v.w;
    }

    const int ty = t >> 4;     // 0..15: tokens ty*4..+4
    const int tx = t & 15;     // cols tx*18..+18

    float acc[4][18];
#pragma unroll
    for (int i = 0; i < 4; ++i)
#pragma unroll
        for (int j = 0; j < 18; ++j) acc[i][j] = 0.f;

#pragma unroll 1
    for (int kp = 0; kp < 6; ++kp) {
        __syncthreads();   // (iter 0: covers x staging; later: sw readers done)
        // ---- stage w panel transposed: sw[k][col] = exw[col][kp*16+k] ----
        {
            const float* gp = exw + (size_t)t*96u + (unsigned)(kp*16);   // col=t < 272
#pragma unroll
            for (int k4 = 0; k4 < 4; ++k4) {
                float4 v = *reinterpret_cast<const float4*>(gp + k4*4);
                sw[(k4*4+0)*292 + t] = v.x;
                sw[(k4*4+1)*292 + t] = v.y;
                sw[(k4*4+2)*292 + t] = v.z;
                sw[(k4*4+3)*292 + t] = v.w;
            }
            if (t < 32) {
                int col = 256 + t;
                if (col < 272) {
                    const float* gp2 = exw + (size_t)col*96u + (unsigned)(kp*16);
#pragma unroll
                    for (int k4 = 0; k4 < 4; ++k4) {
                        float4 v = *reinterpret_cast<const float4*>(gp2 + k4*4);
                        sw[(k4*4+0)*292 + col] = v.x;
                        sw[(k4*4+1)*292 + col] = v.y;
                        sw[(k4*4+2)*292 + col] = v.z;
                        sw[(k4*4+3)*292 + col] = v.w;
                    }
                } else {
#pragma unroll
                    for (int k = 0; k < 16; ++k) sw[k*292 + col] = 0.f;
                }
            }
        }
        __syncthreads();

        // ---- compute 16 k-steps ----
#pragma unroll
        for (int kk = 0; kk < 16; ++kk) {
            float xv[4];
#pragma unroll
            for (int i = 0; i < 4; ++i)
                xv[i] = sx[(ty*4 + i)*97 + kp*16 + kk];
            const float* wrow = sw + kk*292 + tx*18;
            float wv[18];
#pragma unroll
            for (int j2 = 0; j2 < 9; ++j2) {
                float2 w2 = *reinterpret_cast<const float2*>(wrow + j2*2);
                wv[2*j2] = w2.x; wv[2*j2+1] = w2.y;
            }
#pragma unroll
            for (int i = 0; i < 4; ++i)
#pragma unroll
                for (int j = 0; j < 18; ++j)
                    acc[i][j] = fmaf(xv[i], wv[j], acc[i][j]);
        }
    }

    // ---- store (guard padded cols) ----
#pragma unroll
    for (int i = 0; i < 4; ++i) {
        size_t ob = (size_t)(m0 + (unsigned)(ty*4 + i))*512u + 240u;
#pragma unroll
        for (int j = 0; j < 18; ++j) {
            int col = tx*18 + j;
            if (col < 272) out[ob + col] = acc[i][j] + exb[col];
        }
    }
}

// ---------------- launch ----------------
extern "C" void kernel_launch(void* const* d_in, const int* in_sizes, int n_in,
                              void* d_out, int out_size, void* d_ws, size_t ws_size,
                              hipStream_t stream)
{
    const float* x    = (const float*)d_in[0];
    const float* aggW = (const float*)d_in[1];
    const float* aggB = (const float*)d_in[2];
    const float* ipw  = (const float*)d_in[3];
    const float* ipb  = (const float*)d_in[4];
    const float* outw = (const float*)d_in[5];
    const float* outb = (const float*)d_in[6];
    const float* exw  = (const float*)d_in[7];
    const float* exb  = (const float*)d_in[8];
    float* out = (float*)d_out;

    float* Wq = (float*)d_ws;                 // 23040 floats
    float* bq = Wq + WQ_FLOATS;               // 720 floats

    setup_wqkv<<<dim3(3), dim3(256), 0, stream>>>(aggW, aggB, ipw, ipb, Wq, bq);
    attn_main<<<dim3((NTOK + 47)/48), dim3(256), 0, stream>>>(x, Wq, bq, outw, outb, out);
    extra_gemm<<<dim3(NTOK/64), dim3(256), 0, stream>>>(x, exw, exb, out);
}

// Round 6
// 741.161 us; speedup vs baseline: 2.8799x; 1.1101x over previous
//
#include <hip/hip_runtime.h>

#define NTOK (32*4096)           // 131072 tokens
#define WQ_FLOATS (5*144*32)     // fused qkv weights

// ---------- setup: fold agg_W/agg_b through in_proj into W_qkv/b_qkv ----------
__global__ void setup_wqkv(const float* __restrict__ aggW,   // (5,48,32)
                           const float* __restrict__ aggB,   // (5,48)
                           const float* __restrict__ ipw,    // (144,48)
                           const float* __restrict__ ipb,    // (144,)
                           float* __restrict__ Wq,           // (5,144,32)
                           float* __restrict__ bq)           // (5,144)
{
    int t = blockIdx.x*256 + threadIdx.x;
    if (t >= 5*144) return;
    int a = t / 144;
    int r = t - a*144;
    float scale = (r < 48) ? 0.20412414523193154f : 1.0f;    // 1/sqrt(24)
    const float* wrow = ipw + r*48;
    float bacc = ipb[r];
    for (int e = 0; e < 48; ++e) bacc += wrow[e]*aggB[a*48 + e];
    bq[t] = bacc*scale;
    for (int d = 0; d < 32; ++d) {
        float acc = 0.f;
        for (int e = 0; e < 48; ++e) acc += wrow[e]*aggW[(a*48 + e)*32 + d];
        Wq[t*32 + d] = acc*scale;
    }
}

__device__ __forceinline__ void load_xchunk(const float* __restrict__ p, float xr[32])
{
    const float4* xv = reinterpret_cast<const float4*>(p);
#pragma unroll
    for (int i = 0; i < 8; ++i) {
        float4 t = xv[i];
        xr[4*i+0] = t.x; xr[4*i+1] = t.y; xr[4*i+2] = t.z; xr[4*i+3] = t.w;
    }
}

// 32-term dot vs LDS weight row; 4 accumulators -> dep chain ~32cy instead of 128cy
__device__ __forceinline__ float row32(const float* __restrict__ wrow, const float xr[32], float bias)
{
    const float4* wp = reinterpret_cast<const float4*>(wrow);
    float a0 = bias, a1 = 0.f, a2 = 0.f, a3 = 0.f;
#pragma unroll
    for (int i = 0; i < 2; ++i) {
        float4 w4 = wp[i];
        a0 = fmaf(w4.x, xr[4*i+0], a0); a0 = fmaf(w4.y, xr[4*i+1], a0);
        a0 = fmaf(w4.z, xr[4*i+2], a0); a0 = fmaf(w4.w, xr[4*i+3], a0);
    }
#pragma unroll
    for (int i = 2; i < 4; ++i) {
        float4 w4 = wp[i];
        a1 = fmaf(w4.x, xr[4*i+0], a1); a1 = fmaf(w4.y, xr[4*i+1], a1);
        a1 = fmaf(w4.z, xr[4*i+2], a1); a1 = fmaf(w4.w, xr[4*i+3], a1);
    }
#pragma unroll
    for (int i = 4; i < 6; ++i) {
        float4 w4 = wp[i];
        a2 = fmaf(w4.x, xr[4*i+0], a2); a2 = fmaf(w4.y, xr[4*i+1], a2);
        a2 = fmaf(w4.z, xr[4*i+2], a2); a2 = fmaf(w4.w, xr[4*i+3], a2);
    }
#pragma unroll
    for (int i = 6; i < 8; ++i) {
        float4 w4 = wp[i];
        a3 = fmaf(w4.x, xr[4*i+0], a3); a3 = fmaf(w4.y, xr[4*i+1], a3);
        a3 = fmaf(w4.z, xr[4*i+2], a3); a3 = fmaf(w4.w, xr[4*i+3], a3);
    }
    return (a0 + a1) + (a2 + a3);
}

// ---------- attention path: one thread = one (token, row); rolled phases ----------
__global__ __launch_bounds__(256) void attn_main(
    const float* __restrict__ x,     // (32,4096,256)
    const float* __restrict__ Wq,    // (5,144,32) fused
    const float* __restrict__ bq,    // (5,144)
    const float* __restrict__ outw,  // (48,48)
    const float* __restrict__ outb,  // (48,)
    float* __restrict__ out)         // (32,4096,512), cols [0,240)
{
    __shared__ float sAll[11856];
    float* sW   = sAll;           // [2][144*32]
    float* sB   = sAll + 9216;    // [2][144]
    float* sOWT = sAll + 9504;    // [48][48]: sOWT[f*48+j] = outw[j*48+f]
    float* sOB  = sAll + 11808;   // [48]

    const int t = (int)threadIdx.x;
    const unsigned g0 = blockIdx.x * 240u;
    const unsigned u0 = g0 >> 12;
    const unsigned a0 = u0 - 5u*((u0*52429u) >> 18);
    const unsigned a1 = (a0 == 4u) ? 0u : a0 + 1u;

    // ---- stage weights (all 256 threads) ----
    {
        const float4* s0p = reinterpret_cast<const float4*>(Wq + a0*4608u);
        const float4* s1p = reinterpret_cast<const float4*>(Wq + a1*4608u);
        float4* d0 = reinterpret_cast<float4*>(sW);
        float4* d1 = reinterpret_cast<float4*>(sW + 4608);
#pragma unroll
        for (int i = 0; i < 5; ++i) {
            int idx = t + 256*i;
            if (idx < 1152) { d0[idx] = s0p[idx]; d1[idx] = s1p[idx]; }
        }
#pragma unroll
        for (int i = 0; i < 9; ++i) {           // 2304 = 9*256 exactly
            int idx = t + 256*i;
            int f = idx / 48, j = idx - f*48;
            sOWT[idx] = outw[j*48 + f];
        }
        if (t < 144) { sB[t] = bq[a0*144u + t]; sB[144 + t] = bq[a1*144u + t]; }
        if (t >= 192 && t < 240) sOB[t - 192] = outb[t - 192];
    }
    __syncthreads();

    const int lane = t & 63;
    if (lane >= 60) return;
    const int wv = t >> 6;
    const unsigned m_base = (blockIdx.x*4u + (unsigned)wv)*12u;
    const unsigned tok5 = (unsigned)lane / 5u;
    const unsigned aq   = (unsigned)lane - tok5*5u;
    const unsigned m = m_base + tok5;
    if (m >= NTOK) return;

    const unsigned g  = 5u*m_base + (unsigned)lane;     // == 5m + aq
    const unsigned u  = g >> 12;
    const unsigned bb = (u*52429u) >> 18;
    const unsigned a  = u - 5u*bb;
    const float* xp = x + ((((bb<<12) | (g & 4095u)) << 8) + (a<<5));

    const int sel = (a == a0) ? 0 : 1;
    const float* myW = sW + sel*4608;
    const float* myB = sB + sel*144;

    float xr[32]; load_xchunk(xp, xr);

    const int base4 = (lane - (int)aq)*4;
    int ad[4];
#pragma unroll
    for (int r = 0; r < 4; ++r) {
        int sl = (int)aq + r + 1; if (sl >= 5) sl -= 5;
        ad[r] = base4 + sl*4;
    }

    // ---------- QK: stream q_e,k_e; accumulate scores ----------
    float s0[5] = {0,0,0,0,0}, s1[5] = {0,0,0,0,0};
#pragma unroll 1
    for (int e = 0; e < 24; ++e) {
        float qe = row32(myW + e*32, xr, myB[e]);
        float ke = row32(myW + (48+e)*32, xr, myB[48+e]);
        s0[0] = fmaf(qe, ke, s0[0]);
#pragma unroll
        for (int r = 0; r < 4; ++r) {
            float kr = __int_as_float(__builtin_amdgcn_ds_bpermute(ad[r], __float_as_int(ke)));
            s0[r+1] = fmaf(qe, kr, s0[r+1]);
        }
    }
#pragma unroll 1
    for (int e = 24; e < 48; ++e) {
        float qe = row32(myW + e*32, xr, myB[e]);
        float ke = row32(myW + (48+e)*32, xr, myB[48+e]);
        s1[0] = fmaf(qe, ke, s1[0]);
#pragma unroll
        for (int r = 0; r < 4; ++r) {
            float kr = __int_as_float(__builtin_amdgcn_ds_bpermute(ad[r], __float_as_int(ke)));
            s1[r+1] = fmaf(qe, kr, s1[r+1]);
        }
    }

    // ---------- softmax (1/sqrt(24) folded into q weights) ----------
    float p0[5], p1[5];
    {
        float mx = fmaxf(fmaxf(fmaxf(s0[0], s0[1]), fmaxf(s0[2], s0[3])), s0[4]);
        float e0 = __expf(s0[0]-mx), e1 = __expf(s0[1]-mx), e2 = __expf(s0[2]-mx),
              e3 = __expf(s0[3]-mx), e4 = __expf(s0[4]-mx);
        float inv = 1.0f/(e0+e1+e2+e3+e4);
        p0[0]=e0*inv; p0[1]=e1*inv; p0[2]=e2*inv; p0[3]=e3*inv; p0[4]=e4*inv;
    }
    {
        float mx = fmaxf(fmaxf(fmaxf(s1[0], s1[1]), fmaxf(s1[2], s1[3])), s1[4]);
        float e0 = __expf(s1[0]-mx), e1 = __expf(s1[1]-mx), e2 = __expf(s1[2]-mx),
              e3 = __expf(s1[3]-mx), e4 = __expf(s1[4]-mx);
        float inv = 1.0f/(e0+e1+e2+e3+e4);
        p1[0]=e0*inv; p1[1]=e1*inv; p1[2]=e2*inv; p1[3]=e3*inv; p1[4]=e4*inv;
    }

    // ---------- V + fused out-proj: out[j] += owT[e][j] * o_e ----------
    float oj[48];
    {
        const float4* b4 = reinterpret_cast<const float4*>(sOB);
#pragma unroll
        for (int j4 = 0; j4 < 12; ++j4) {
            float4 v = b4[j4];
            oj[4*j4+0]=v.x; oj[4*j4+1]=v.y; oj[4*j4+2]=v.z; oj[4*j4+3]=v.w;
        }
    }
#pragma unroll 1
    for (int e = 0; e < 24; ++e) {
        float ve = row32(myW + (96+e)*32, xr, myB[96+e]);
        float oe = p0[0]*ve;
#pragma unroll
        for (int r = 0; r < 4; ++r) {
            float vr = __int_as_float(__builtin_amdgcn_ds_bpermute(ad[r], __float_as_int(ve)));
            oe = fmaf(p0[r+1], vr, oe);
        }
        const float4* owr = reinterpret_cast<const float4*>(sOWT + e*48);
#pragma unroll
        for (int j4 = 0; j4 < 12; ++j4) {
            float4 w4 = owr[j4];
            oj[4*j4+0] = fmaf(w4.x, oe, oj[4*j4+0]);
            oj[4*j4+1] = fmaf(w4.y, oe, oj[4*j4+1]);
            oj[4*j4+2] = fmaf(w4.z, oe, oj[4*j4+2]);
            oj[4*j4+3] = fmaf(w4.w, oe, oj[4*j4+3]);
        }
    }
#pragma unroll 1
    for (int e = 24; e < 48; ++e) {
        float ve = row32(myW + (96+e)*32, xr, myB[96+e]);
        float oe = p1[0]*ve;
#pragma unroll
        for (int r = 0; r < 4; ++r) {
            float vr = __int_as_float(__builtin_amdgcn_ds_bpermute(ad[r], __float_as_int(ve)));
            oe = fmaf(p1[r+1], vr, oe);
        }
        const float4* owr = reinterpret_cast<const float4*>(sOWT + e*48);
#pragma unroll
        for (int j4 = 0; j4 < 12; ++j4) {
            float4 w4 = owr[j4];
            oj[4*j4+0] = fmaf(w4.x, oe, oj[4*j4+0]);
            oj[4*j4+1] = fmaf(w4.y, oe, oj[4*j4+1]);
            oj[4*j4+2] = fmaf(w4.z, oe, oj[4*j4+2]);
            oj[4*j4+3] = fmaf(w4.w, oe, oj[4*j4+3]);
        }
    }

    // ---------- store 48 cols ----------
    float4* d4 = reinterpret_cast<float4*>(out + (size_t)m*512u + aq*48u);
#pragma unroll
    for (int j4 = 0; j4 < 12; ++j4)
        d4[j4] = make_float4(oj[4*j4+0], oj[4*j4+1], oj[4*j4+2], oj[4*j4+3]);
}

// ---------- extra path v3: one thread = one token; w-half in LDS (staged once) ----------
// Grid: (token_block 0..511) x (col half 0..1). Block: 256 tokens, 136 cols (34 f4).
// LDS: sw[c4][k][j] = exw[colbase + c4*4 + j][k]  (13056 floats = 52224 B).
// Inner loop: uniform-broadcast ds_read_b128 + 4 FMA chains; f4 stores (full lines).
__global__ __launch_bounds__(256) void extra_gemm(
    const float* __restrict__ x,     // (32,4096,256)
    const float* __restrict__ exw,   // (272,96)
    const float* __restrict__ exb,   // (272,)
    float* __restrict__ out)         // cols [240,512)
{
    __shared__ float sw[34*96*4];    // 52224 B

    const int t = (int)threadIdx.x;
    const unsigned tb = blockIdx.x >> 1;
    const int half = (int)(blockIdx.x & 1u);
    const int colbase = half*136;

    // ---- stage transposed w-half: 3264 f4 chunks of exw ----
#pragma unroll 1
    for (int q = t; q < 3264; q += 256) {
        int row = q / 24;                 // local col 0..135
        int kp  = (q - row*24)*4;         // k 0..92
        float4 v = *reinterpret_cast<const float4*>(
            exw + (size_t)(colbase + row)*96u + (unsigned)kp);
        int c4 = row >> 2, jp = row & 3;
        float* dp = sw + (c4*96 + kp)*4 + jp;
        dp[0] = v.x; dp[4] = v.y; dp[8] = v.z; dp[12] = v.w;
    }

    // ---- my token's x into 96 registers (6 full 64B lines, all bytes used) ----
    const unsigned m = tb*256u + (unsigned)t;
    float xr[96];
    {
        const float4* xp = reinterpret_cast<const float4*>(x + (size_t)m*256u + 160u);
#pragma unroll
        for (int i = 0; i < 24; ++i) {
            float4 v = xp[i];
            xr[4*i+0]=v.x; xr[4*i+1]=v.y; xr[4*i+2]=v.z; xr[4*i+3]=v.w;
        }
    }
    __syncthreads();

    float* __restrict__ dst = out + (size_t)m*512u + 240u + (unsigned)colbase;
    const float4* bp = reinterpret_cast<const float4*>(exb + colbase);
#pragma unroll 1
    for (int c4 = 0; c4 < 34; ++c4) {
        const float4* wp = reinterpret_cast<const float4*>(sw + c4*384);
        float4 acc = bp[c4];
#pragma unroll
        for (int k = 0; k < 96; ++k) {
            float4 w4 = wp[k];
            acc.x = fmaf(w4.x, xr[k], acc.x);
            acc.y = fmaf(w4.y, xr[k], acc.y);
            acc.z = fmaf(w4.z, xr[k], acc.z);
            acc.w = fmaf(w4.w, xr[k], acc.w);
        }
        reinterpret_cast<float4*>(dst)[c4] = acc;
    }
}

// ---------------- launch ----------------
extern "C" void kernel_launch(void* const* d_in, const int* in_sizes, int n_in,
                              void* d_out, int out_size, void* d_ws, size_t ws_size,
                              hipStream_t stream)
{
    const float* x    = (const float*)d_in[0];
    const float* aggW = (const float*)d_in[1];
    const float* aggB = (const float*)d_in[2];
    const float* ipw  = (const float*)d_in[3];
    const float* ipb  = (const float*)d_in[4];
    const float* outw = (const float*)d_in[5];
    const float* outb = (const float*)d_in[6];
    const float* exw  = (const float*)d_in[7];
    const float* exb  = (const float*)d_in[8];
    float* out = (float*)d_out;

    float* Wq = (float*)d_ws;                 // 23040 floats
    float* bq = Wq + WQ_FLOATS;               // 720 floats

    setup_wqkv<<<dim3(3), dim3(256), 0, stream>>>(aggW, aggB, ipw, ipb, Wq, bq);
    attn_main<<<dim3((NTOK + 47)/48), dim3(256), 0, stream>>>(x, Wq, bq, outw, outb, out);
    // 512 token-blocks x 2 column halves
    extra_gemm<<<dim3(512*2), dim3(256), 0, stream>>>(x, exw, exb, out);
}